// Round 1
// baseline (1116.019 us; speedup 1.0000x reference)
//
#include <hip/hip_runtime.h>

#define NT   10000
#define NT1  10001
#define DTF  0.1f

// Semi-implicit Euler for the 6-state PBPK-style ODE.
// M = I - dt*A is block lower-triangular:
//   [a b      ]   a = 1+dt*(k2+k3+lp)   b = -dt*k4
//   [c d      ]   c = -dt*k3            d = 1+dt*(k4+k5+lp)
//   [  e2     ]   e2 = 1+dt*(k6+lp), coupled to x1 via -dt*k5
//   [lp  a2 b ]   a2 = a - dt*lp
//   [ lp c d2 ]   d2 = d - dt*lp
//   [  lp  e5 ]   e5 = 1+dt*k6, coupled to x4 via -dt*k5
// Solve: 2x2 Cramer for (x0,x1); x2; 2x2 Cramer for (x3,x4); x5.
__global__ __launch_bounds__(256)
void fwdode_kernel(const float* __restrict__ theta,
                   const float* __restrict__ P0,
                   float* __restrict__ out) {
    if (blockIdx.x != 0) {
        // Concurrent block: fill T row and PP[:,0] (out buffer is poisoned).
        for (int i = threadIdx.x; i < NT1; i += 256)
            out[6 * NT1 + i] = (float)i * DTF;
        if (threadIdx.x < 6)
            out[threadIdx.x * NT1] = P0[threadIdx.x];
        return;
    }
    if (threadIdx.x != 0) return;   // one thread runs the sequential chain

    const float k1 = theta[0], k2 = theta[1], k4 = theta[2],
                k5 = theta[3], k6 = theta[4];
    const float lp   = 7e-5f;
    const float dt   = DTF;
    const float dtZ  = dt * 46.0f;        // dt*Z
    const float C0   = dtZ * 2000.0f;     // dt*Z*Y
    const float A0   = 1.0f + dt * (k2 + lp) + C0;  // a = A0 - dtZ*u
    const float b    = -dt * k4;
    const float d    = 1.0f + dt * (k4 + k5 + lp);
    const float d2   = 1.0f + dt * (k4 + k5);
    const float dtlp = dt * lp;
    const float re2  = 1.0f / (1.0f + dt * (k6 + lp));
    const float re5  = 1.0f / (1.0f + dt * k6);
    const float dtk5 = dt * k5;
    const float c10  = dt * k1 * 122.9f;  // dt*k1*10*12.29 (S0 coeff)
    const float c1   = dt * k1 * 12.29f;  // dt*k1*12.29    (S3 coeff)

    float p0 = P0[0], p1 = P0[1], p2 = P0[2],
          p3 = P0[3], p4 = P0[4], p5 = P0[5];
    float u = p1 + p4;                    // only state feeding the matrix

    float* __restrict__ o = out + 1;      // column i+1 base
    for (int i = 0; i < NT; ++i) {
        const float t  = (float)i * dt;
        const float ev = __expf(-0.008605f * t);       // Pv/12.29, off-chain
        const float r0 = fmaf(c10, ev, p0);            // p0 + dt*S0
        const float r3 = fmaf(c1,  ev, p3);            // p3 + dt*S3

        const float a   = fmaf(-dtZ, u, A0);           // 1+dt*(k2+k3+lp)
        const float cc  = fmaf(dtZ, u, -C0);           // -dt*k3
        const float bc  = b * cc;
        const float det1  = fmaf(a, d, -bc);
        const float rdet1 = __builtin_amdgcn_rcpf(det1);
        const float n0 = fmaf(d, r0, -(b * p1));
        const float n1 = fmaf(a, p1, -(cc * r0));
        const float x0 = n0 * rdet1;
        const float x1 = n1 * rdet1;

        const float x2 = fmaf(dtk5, x1, p2) * re2;

        const float a2    = a - dtlp;
        const float det2  = fmaf(a2, d2, -bc);
        const float rdet2 = __builtin_amdgcn_rcpf(det2);
        const float r3p = fmaf(dtlp, x0, r3);
        const float r4p = fmaf(dtlp, x1, p4);
        const float n3 = fmaf(d2, r3p, -(b * r4p));
        const float n4 = fmaf(a2, r4p, -(cc * r3p));
        const float x3 = n3 * rdet2;
        const float x4 = n4 * rdet2;

        const float x5 = fmaf(dtlp, x2, fmaf(dtk5, x4, p5)) * re5;

        o[0 * NT1 + i] = x0;
        o[1 * NT1 + i] = x1;
        o[2 * NT1 + i] = x2;
        o[3 * NT1 + i] = x3;
        o[4 * NT1 + i] = x4;
        o[5 * NT1 + i] = x5;

        p0 = x0; p1 = x1; p2 = x2; p3 = x3; p4 = x4; p5 = x5;
        u = x1 + x4;   // feeds next step's matrix
    }
}

extern "C" void kernel_launch(void* const* d_in, const int* in_sizes, int n_in,
                              void* d_out, int out_size, void* d_ws, size_t ws_size,
                              hipStream_t stream) {
    const float* theta = (const float*)d_in[0];
    const float* P0    = (const float*)d_in[1];
    float* out = (float*)d_out;
    hipLaunchKernelGGL(fwdode_kernel, dim3(2), dim3(256), 0, stream,
                       theta, P0, out);
}

// Round 2
// 317.563 us; speedup vs baseline: 3.5143x; 3.5143x over previous
//
#include <hip/hip_runtime.h>

#define NT   10000
#define NT1  10001
#define KCH  20
#define NCH  500      // 500 * 20 = 10000
#define BLOCK 512

// Decomposition:
//  w0=p0+p3, w1=p1+p4 close under the implicit-Euler step (lp terms cancel):
//   [1+dt(k2+k3), -dt k4 ; -dt k3, 1+dt(k4+k5)] [w0';w1'] = [w0+s ; w1],
//   s = dt*k1*11*12.29*ev,  k3 = Z*v,  v = Y - w1.
//  Phase 1 (1 thread): v-recurrence  v' = (E0 + v*(E1 - dtZ*g) + dtZ*v^2)/det,
//   det = D0 + D1*v,  g = w0 + s,  w0' = (d2*g + C4 - dtk4*v)/det.  v -> LDS.
//  Phase 2 (500 threads): given v[n], rows (0,1) are a 2x2 affine time-varying
//   recurrence -> parallel scan; w0 scalar affine scan; x3=w0-x0, x4=w1-x1;
//   x2, x5 scalar affine scans (constant multiplier).
__global__ __launch_bounds__(BLOCK)
void fwdode_kernel(const float* __restrict__ theta,
                   const float* __restrict__ P0,
                   float* __restrict__ out) {
    __shared__ float v_lds[NT1];
    __shared__ float sm00[NCH], sm01[NCH], sm10[NCH], sm11[NCH];
    __shared__ float sh0[NCH], sh1[NCH], smw[NCH], shw[NCH];

    const int tid = threadIdx.x;
    const float dt = 0.1f, Zc = 46.0f, Yc = 2000.0f, lp = 7e-5f;
    const float k1 = theta[0], k2 = theta[1], k4 = theta[2],
                k5 = theta[3], k6 = theta[4];
    const float dtZ   = dt * Zc;
    const float beta  = 1.0f + dt * k2;
    const float d2    = 1.0f + dt * (k4 + k5);
    const float D0    = beta * d2;
    const float D1    = dtZ * (1.0f + dt * k5);
    const float E0    = beta * Yc * dt * (k4 + k5);
    const float E1    = beta + dt * dt * Zc * Yc * k5;
    const float C4    = dt * k4 * Yc;
    const float cs    = dt * k1 * 135.19f;   // s_n   = cs  * ev_n  (w source)
    const float c10   = dt * k1 * 122.9f;    // s0_n  = c10 * ev_n  (x0 source)
    const float dtk4  = dt * k4;
    const float dtk5  = dt * k5;
    const float dtlp  = dt * lp;
    const float rho   = __expf(-0.0008605f); // ev_{n+1} = rho * ev_n
    const float re2   = 1.0f / (1.0f + dt * (k6 + lp));
    const float re5   = 1.0f / (1.0f + dt * k6);
    const float dd    = d2 + dt * lp;        // d  in (x0,x1) block
    const float bb    = -dtk4;               // b
    const float betal = 1.0f + dt * (k2 + lp);

    // ---- Phase 0 / Phase 1 ----
    if (tid == 0) {
        float v  = Yc - (P0[1] + P0[4]);
        float w0 = P0[0] + P0[3];
        v_lds[0] = v;
        int n = 0;
        for (int outer = 0; outer < 40; ++outer) {
            float ev = __expf(-0.0008605f * (float)n);  // exact refresh
            float g  = fmaf(cs, ev, w0);
            #pragma unroll 5
            for (int inner = 0; inner < 250; ++inner) {
                const float det  = fmaf(D1, v, D0);
                const float rdet = __builtin_amdgcn_rcpf(det);
                const float h    = fmaf(-dtZ, g, E1);
                const float t    = fmaf(dtZ, v, h);
                const float Mv   = fmaf(t, v, E0);
                const float q    = fmaf(d2, g, C4);
                const float Nw0  = fmaf(-dtk4, v, q);
                v  = Mv  * rdet;
                w0 = Nw0 * rdet;
                ev *= rho;
                g = fmaf(cs, ev, w0);
                v_lds[n + 1] = v;
                ++n;
            }
        }
    } else if (tid >= 64) {
        for (int i = tid - 64; i < NT1; i += BLOCK - 64)
            out[6 * NT1 + i] = (float)i * dt;            // T row
        if (tid - 64 < 6) out[(tid - 64) * NT1] = P0[tid - 64];  // column 0
    }
    __syncthreads();

    // ---- Phase 2, stage 1: (x0,x1) 2x2 affine scan + w0 scalar scan ----
    const int c  = tid;
    const int n0 = c * KCH;
    if (c < NCH) {
        float M00 = 1.0f, M01 = 0.0f, M10 = 0.0f, M11 = 1.0f;
        float h0 = 0.0f, h1 = 0.0f, mw = 1.0f, hw = 0.0f;
        float ev = __expf(-0.0008605f * (float)n0);
        for (int j = 0; j < KCH; ++j) {
            const int   n    = n0 + j;
            const float vn   = v_lds[n];
            const float an   = fmaf(dtZ, vn, betal);
            const float cn   = -dtZ * vn;
            const float det1 = an * dd - bb * cn;
            const float r1   = 1.0f / det1;
            const float s0   = c10 * ev;
            const float A00 = r1 * dd,  A01 = -r1 * bb;
            const float A10 = -r1 * cn, A11 = r1 * an;
            const float nM00 = A00 * M00 + A01 * M10;
            const float nM01 = A00 * M01 + A01 * M11;
            const float nM10 = A10 * M00 + A11 * M10;
            const float nM11 = A10 * M01 + A11 * M11;
            const float nh0  = A00 * h0 + A01 * h1 + s0 * A00;
            const float nh1  = A10 * h0 + A11 * h1 + s0 * A10;
            M00 = nM00; M01 = nM01; M10 = nM10; M11 = nM11;
            h0 = nh0; h1 = nh1;
            const float det = fmaf(D1, vn, D0);
            const float rd  = 1.0f / det;
            const float pw  = rd * d2;
            const float ow  = rd * (fmaf(d2, cs * ev, C4) - dtk4 * vn);
            mw = pw * mw;
            hw = fmaf(pw, hw, ow);
            ev *= rho;
        }
        sm00[c] = M00; sm01[c] = M01; sm10[c] = M10; sm11[c] = M11;
        sh0[c] = h0;   sh1[c] = h1;   smw[c] = mw;   shw[c] = hw;
    }
    __syncthreads();
    for (int off = 1; off < NCH; off <<= 1) {
        float n00, n01, n10, n11, nh0, nh1, nmw, nhw;
        const bool act = (c < NCH) && (c >= off);
        if (act) {
            const int e = c - off;
            const float a00 = sm00[c], a01 = sm01[c], a10 = sm10[c], a11 = sm11[c];
            const float b0 = sh0[c], b1 = sh1[c], aw = smw[c], bw = shw[c];
            const float e00 = sm00[e], e01 = sm01[e], e10 = sm10[e], e11 = sm11[e];
            const float f0 = sh0[e], f1 = sh1[e], ew = smw[e], fw = shw[e];
            n00 = a00 * e00 + a01 * e10;  n01 = a00 * e01 + a01 * e11;
            n10 = a10 * e00 + a11 * e10;  n11 = a10 * e01 + a11 * e11;
            nh0 = a00 * f0 + a01 * f1 + b0;
            nh1 = a10 * f0 + a11 * f1 + b1;
            nmw = aw * ew;  nhw = fmaf(aw, fw, bw);
        }
        __syncthreads();
        if (act) {
            sm00[c] = n00; sm01[c] = n01; sm10[c] = n10; sm11[c] = n11;
            sh0[c] = nh0; sh1[c] = nh1; smw[c] = nmw; shw[c] = nhw;
        }
        __syncthreads();
    }
    if (c < NCH) {
        float x0 = P0[0], x1 = P0[1], w0s = P0[0] + P0[3];
        if (c > 0) {
            const int e = c - 1;
            const float X0 = x0, X1 = x1, W0 = w0s;
            x0  = sm00[e] * X0 + sm01[e] * X1 + sh0[e];
            x1  = sm10[e] * X0 + sm11[e] * X1 + sh1[e];
            w0s = fmaf(smw[e], W0, shw[e]);
        }
        float ev = __expf(-0.0008605f * (float)n0);
        for (int j = 0; j < KCH; ++j) {
            const int   n    = n0 + j;
            const float vn   = v_lds[n];
            const float an   = fmaf(dtZ, vn, betal);
            const float cn   = -dtZ * vn;
            const float det1 = an * dd - bb * cn;
            const float r1   = 1.0f / det1;
            const float s0   = c10 * ev;
            const float t0   = x0 + s0;
            const float nx0  = r1 * (dd * t0 - bb * x1);
            const float nx1  = r1 * fmaf(an, x1, -cn * t0);
            const float det = fmaf(D1, vn, D0);
            const float rd  = 1.0f / det;
            const float ow  = rd * (fmaf(d2, cs * ev, C4) - dtk4 * vn);
            w0s = fmaf(rd * d2, w0s, ow);
            const float w1n1 = Yc - v_lds[n + 1];
            out[0 * NT1 + 1 + n] = nx0;
            out[1 * NT1 + 1 + n] = nx1;
            out[3 * NT1 + 1 + n] = w0s - nx0;
            out[4 * NT1 + 1 + n] = w1n1 - nx1;
            x0 = nx0; x1 = nx1;
            ev *= rho;
        }
    }
    __threadfence();
    __syncthreads();

    // ---- stage 2: x2 scalar affine scan (x2' = re2*(x2 + dtk5*x1')) ----
    if (c < NCH) {
        float m2 = 1.0f, o2 = 0.0f;
        for (int j = 0; j < KCH; ++j) {
            const float x1v = out[1 * NT1 + 1 + n0 + j];
            m2 *= re2;
            o2 = fmaf(re2, o2, re2 * dtk5 * x1v);
        }
        smw[c] = m2; shw[c] = o2;
    }
    __syncthreads();
    for (int off = 1; off < NCH; off <<= 1) {
        float nm, no;
        const bool act = (c < NCH) && (c >= off);
        if (act) { nm = smw[c] * smw[c - off]; no = fmaf(smw[c], shw[c - off], shw[c]); }
        __syncthreads();
        if (act) { smw[c] = nm; shw[c] = no; }
        __syncthreads();
    }
    if (c < NCH) {
        float x2s = P0[2];
        if (c > 0) x2s = fmaf(smw[c - 1], x2s, shw[c - 1]);
        for (int j = 0; j < KCH; ++j) {
            const int n = n0 + j;
            const float x1v = out[1 * NT1 + 1 + n];
            x2s = re2 * fmaf(dtk5, x1v, x2s);
            out[2 * NT1 + 1 + n] = x2s;
        }
    }
    __threadfence();
    __syncthreads();

    // ---- stage 3: x5 scalar affine scan (x5' = re5*(x5 + dtk5*x4' + dtlp*x2')) ----
    if (c < NCH) {
        float m3 = 1.0f, o3 = 0.0f;
        for (int j = 0; j < KCH; ++j) {
            const int n = n0 + j;
            const float x4v = out[4 * NT1 + 1 + n];
            const float x2v = out[2 * NT1 + 1 + n];
            const float qn  = fmaf(dtk5, x4v, dtlp * x2v);
            m3 *= re5;
            o3 = fmaf(re5, o3, re5 * qn);
        }
        smw[c] = m3; shw[c] = o3;
    }
    __syncthreads();
    for (int off = 1; off < NCH; off <<= 1) {
        float nm, no;
        const bool act = (c < NCH) && (c >= off);
        if (act) { nm = smw[c] * smw[c - off]; no = fmaf(smw[c], shw[c - off], shw[c]); }
        __syncthreads();
        if (act) { smw[c] = nm; shw[c] = no; }
        __syncthreads();
    }
    if (c < NCH) {
        float x5s = P0[5];
        if (c > 0) x5s = fmaf(smw[c - 1], x5s, shw[c - 1]);
        for (int j = 0; j < KCH; ++j) {
            const int n = n0 + j;
            const float x4v = out[4 * NT1 + 1 + n];
            const float x2v = out[2 * NT1 + 1 + n];
            x5s = re5 * (x5s + fmaf(dtk5, x4v, dtlp * x2v));
            out[5 * NT1 + 1 + n] = x5s;
        }
    }
}

extern "C" void kernel_launch(void* const* d_in, const int* in_sizes, int n_in,
                              void* d_out, int out_size, void* d_ws, size_t ws_size,
                              hipStream_t stream) {
    const float* theta = (const float*)d_in[0];
    const float* P0    = (const float*)d_in[1];
    float* out = (float*)d_out;
    hipLaunchKernelGGL(fwdode_kernel, dim3(1), dim3(BLOCK), 0, stream,
                       theta, P0, out);
}

// Round 3
// 63.248 us; speedup vs baseline: 17.6450x; 5.0209x over previous
//
#include <hip/hip_runtime.h>

#define NT    10000
#define NT1   10001
#define KCH   20
#define NCH   500      // phase-2: 500 chunks * 20 steps
#define CSH   250      // shooting: 250 chunks * 40 steps
#define LSH   40
#define NITER 6
#define BLOCK 512

// Phase 1 (multiple shooting, 250 threads): the closed (v,w0) recurrence
//   g = w0 + cs*ev, det = D0 + D1*v,
//   v'  = (E0 + v*(E1 - dtZ*g) + dtZ*v^2)/det,
//   w0' = (d2*g + C4 - dtk4*v)/det
// is solved parallel-in-time: chunk-exact integration + 2x2 Jacobian,
// boundary-mismatch Newton correction via affine scan. Init guess from the
// discrete slow manifold: w1_m = cs*a*(rho^m - a^m)/(rho - a), a=1/(1+dt*k5).
// Phase 2 (500 threads, unchanged from verified round-2 kernel): given v[n],
// (x0,x1) 2x2 affine scan, w0 scalar scan, x3=w0-x0, x4=(Y-v)-x1, then x2,x5
// scalar affine scans.
__global__ __launch_bounds__(BLOCK)
void fwdode_kernel(const float* __restrict__ theta,
                   const float* __restrict__ P0,
                   float* __restrict__ out) {
    __shared__ float v_lds[NT1];
    __shared__ float sm00[NCH], sm01[NCH], sm10[NCH], sm11[NCH];
    __shared__ float sh0[NCH], sh1[NCH], smw[NCH], shw[NCH];

    const int tid = threadIdx.x;
    const float dt = 0.1f, Zc = 46.0f, Yc = 2000.0f, lp = 7e-5f;
    const float k1 = theta[0], k2 = theta[1], k4 = theta[2],
                k5 = theta[3], k6 = theta[4];
    const float dtZ   = dt * Zc;
    const float dtZ2  = 2.0f * dtZ;
    const float beta  = 1.0f + dt * k2;
    const float d2    = 1.0f + dt * (k4 + k5);
    const float D0    = beta * d2;
    const float D1    = dtZ * (1.0f + dt * k5);
    const float E0    = beta * Yc * dt * (k4 + k5);
    const float E1    = beta + dt * dt * Zc * Yc * k5;
    const float C4    = dt * k4 * Yc;
    const float cs    = dt * k1 * 135.19f;
    const float c10   = dt * k1 * 122.9f;
    const float dtk4  = dt * k4;
    const float dtk5  = dt * k5;
    const float dtlp  = dt * lp;
    const float rho   = __expf(-0.0008605f);
    const float re2   = 1.0f / (1.0f + dt * (k6 + lp));
    const float re5   = 1.0f / (1.0f + dt * k6);
    const float dd    = d2 + dt * lp;
    const float bb    = -dtk4;
    const float betal = 1.0f + dt * (k2 + lp);

    const int c = tid;

    // ---- shooting init: slow-manifold closed-form guess ----
    if (c < CSH) {
        float vi, wi;
        if (c == 0) {
            vi = Yc - (P0[1] + P0[4]);
            wi = P0[0] + P0[3];
        } else {
            const float fm     = (float)(c * LSH);
            const float rhon   = __expf(-0.0008605f * fm);
            const float alpha  = 1.0f / (1.0f + dtk5);
            const float alphan = __expf(fm * __logf(alpha));
            const float diff   = rho - alpha;
            float w1;
            if (__builtin_fabsf(diff) > 1e-4f)
                w1 = cs * alpha * (rhon - alphan) / diff;
            else
                w1 = cs * alpha * fm * rhon / rho;
            vi = Yc - w1;
            const float sm = cs * rhon;
            wi = (sm + dtk4 * w1) / (dt * k2 + dtZ * vi);
        }
        smw[c] = vi;   // guess v at chunk start
        shw[c] = wi;   // guess w0 at chunk start
    } else if (tid >= 256) {
        for (int i = tid - 256; i < NT1; i += BLOCK - 256)
            out[6 * NT1 + i] = (float)i * dt;             // T row
        if (tid - 256 < 6) out[(tid - 256) * NT1] = P0[tid - 256];  // col 0
    }
    __syncthreads();

    // ---- Newton / multiple-shooting iterations ----
    for (int it = 0; it < NITER; ++it) {
        float Pv, Pw, J11, J12, J21, J22;
        if (c < CSH) {
            float v = smw[c], w0 = shw[c];
            float ev = __expf(-0.0008605f * (float)(c * LSH));
            J11 = 1.0f; J12 = 0.0f; J21 = 0.0f; J22 = 1.0f;
            #pragma unroll 4
            for (int j = 0; j < LSH; ++j) {
                const float g    = fmaf(cs, ev, w0);
                const float det  = fmaf(D1, v, D0);
                const float rdet = __builtin_amdgcn_rcpf(det);
                const float h    = fmaf(-dtZ, g, E1);
                const float tq   = fmaf(dtZ, v, h);
                const float Nv   = fmaf(tq, v, E0);
                const float q    = fmaf(d2, g, C4);
                const float Nw   = fmaf(-dtk4, v, q);
                const float vn   = Nv * rdet;
                const float wn   = Nw * rdet;
                const float a11  = fmaf(-D1, vn, fmaf(dtZ2, v, h)) * rdet;
                const float a12  = (-dtZ * v) * rdet;
                const float a21  = -fmaf(D1, wn, dtk4) * rdet;
                const float a22  = d2 * rdet;
                const float t11 = a11 * J11 + a12 * J21;
                const float t12 = a11 * J12 + a12 * J22;
                const float t21 = a21 * J11 + a22 * J21;
                const float t22 = a21 * J12 + a22 * J22;
                J11 = t11; J12 = t12; J21 = t21; J22 = t22;
                v = vn; w0 = wn; ev *= rho;
            }
            Pv = v; Pw = w0;
        }
        __syncthreads();
        if (c < CSH) {
            const float r0 = (c < CSH - 1) ? (Pv - smw[c + 1]) : 0.0f;
            const float r1 = (c < CSH - 1) ? (Pw - shw[c + 1]) : 0.0f;
            sm00[c] = J11; sm01[c] = J12; sm10[c] = J21; sm11[c] = J22;
            sh0[c] = r0; sh1[c] = r1;
        }
        __syncthreads();
        for (int off = 1; off < CSH; off <<= 1) {
            float n00, n01, n10, n11, nh0, nh1;
            const bool act = (c < CSH) && (c >= off);
            if (act) {
                const int e = c - off;
                const float a00 = sm00[c], a01 = sm01[c], a10 = sm10[c], a11 = sm11[c];
                const float b0 = sh0[c], b1 = sh1[c];
                const float e00 = sm00[e], e01 = sm01[e], e10 = sm10[e], e11 = sm11[e];
                const float f0 = sh0[e], f1 = sh1[e];
                n00 = a00 * e00 + a01 * e10;  n01 = a00 * e01 + a01 * e11;
                n10 = a10 * e00 + a11 * e10;  n11 = a10 * e01 + a11 * e11;
                nh0 = a00 * f0 + a01 * f1 + b0;
                nh1 = a10 * f0 + a11 * f1 + b1;
            }
            __syncthreads();
            if (act) {
                sm00[c] = n00; sm01[c] = n01; sm10[c] = n10; sm11[c] = n11;
                sh0[c] = nh0; sh1[c] = nh1;
            }
            __syncthreads();
        }
        float nv, nw;
        if (c >= 1 && c < CSH) {
            nv = smw[c] + sh0[c - 1];   // delta_c applied to guess[c]
            nw = shw[c] + sh1[c - 1];
        }
        __syncthreads();
        if (c >= 1 && c < CSH) { smw[c] = nv; shw[c] = nw; }
        __syncthreads();
    }

    // ---- final pass: write v trajectory to LDS ----
    if (c < CSH) {
        float v = smw[c], w0 = shw[c];
        float ev = __expf(-0.0008605f * (float)(c * LSH));
        if (c == 0) v_lds[0] = v;
        const int base = c * LSH;
        #pragma unroll 4
        for (int j = 0; j < LSH; ++j) {
            const float g    = fmaf(cs, ev, w0);
            const float det  = fmaf(D1, v, D0);
            const float rdet = __builtin_amdgcn_rcpf(det);
            const float h    = fmaf(-dtZ, g, E1);
            const float tq   = fmaf(dtZ, v, h);
            const float Nv   = fmaf(tq, v, E0);
            const float q    = fmaf(d2, g, C4);
            const float Nw   = fmaf(-dtk4, v, q);
            v  = Nv * rdet;
            w0 = Nw * rdet;
            ev *= rho;
            v_lds[base + j + 1] = v;
        }
    }
    __syncthreads();

    // ---- Phase 2, stage 1: (x0,x1) 2x2 affine scan + w0 scalar scan ----
    const int n0 = c * KCH;
    if (c < NCH) {
        float M00 = 1.0f, M01 = 0.0f, M10 = 0.0f, M11 = 1.0f;
        float h0 = 0.0f, h1 = 0.0f, mw = 1.0f, hw = 0.0f;
        float ev = __expf(-0.0008605f * (float)n0);
        for (int j = 0; j < KCH; ++j) {
            const int   n    = n0 + j;
            const float vn   = v_lds[n];
            const float an   = fmaf(dtZ, vn, betal);
            const float cn   = -dtZ * vn;
            const float det1 = an * dd - bb * cn;
            const float r1   = 1.0f / det1;
            const float s0   = c10 * ev;
            const float A00 = r1 * dd,  A01 = -r1 * bb;
            const float A10 = -r1 * cn, A11 = r1 * an;
            const float nM00 = A00 * M00 + A01 * M10;
            const float nM01 = A00 * M01 + A01 * M11;
            const float nM10 = A10 * M00 + A11 * M10;
            const float nM11 = A10 * M01 + A11 * M11;
            const float nh0  = A00 * h0 + A01 * h1 + s0 * A00;
            const float nh1  = A10 * h0 + A11 * h1 + s0 * A10;
            M00 = nM00; M01 = nM01; M10 = nM10; M11 = nM11;
            h0 = nh0; h1 = nh1;
            const float det = fmaf(D1, vn, D0);
            const float rd  = 1.0f / det;
            const float pw  = rd * d2;
            const float ow  = rd * (fmaf(d2, cs * ev, C4) - dtk4 * vn);
            mw = pw * mw;
            hw = fmaf(pw, hw, ow);
            ev *= rho;
        }
        sm00[c] = M00; sm01[c] = M01; sm10[c] = M10; sm11[c] = M11;
        sh0[c] = h0;   sh1[c] = h1;   smw[c] = mw;   shw[c] = hw;
    }
    __syncthreads();
    for (int off = 1; off < NCH; off <<= 1) {
        float n00, n01, n10, n11, nh0, nh1, nmw, nhw;
        const bool act = (c < NCH) && (c >= off);
        if (act) {
            const int e = c - off;
            const float a00 = sm00[c], a01 = sm01[c], a10 = sm10[c], a11 = sm11[c];
            const float b0 = sh0[c], b1 = sh1[c], aw = smw[c], bw = shw[c];
            const float e00 = sm00[e], e01 = sm01[e], e10 = sm10[e], e11 = sm11[e];
            const float f0 = sh0[e], f1 = sh1[e], ew = smw[e], fw = shw[e];
            n00 = a00 * e00 + a01 * e10;  n01 = a00 * e01 + a01 * e11;
            n10 = a10 * e00 + a11 * e10;  n11 = a10 * e01 + a11 * e11;
            nh0 = a00 * f0 + a01 * f1 + b0;
            nh1 = a10 * f0 + a11 * f1 + b1;
            nmw = aw * ew;  nhw = fmaf(aw, fw, bw);
        }
        __syncthreads();
        if (act) {
            sm00[c] = n00; sm01[c] = n01; sm10[c] = n10; sm11[c] = n11;
            sh0[c] = nh0; sh1[c] = nh1; smw[c] = nmw; shw[c] = nhw;
        }
        __syncthreads();
    }
    if (c < NCH) {
        float x0 = P0[0], x1 = P0[1], w0s = P0[0] + P0[3];
        if (c > 0) {
            const int e = c - 1;
            const float X0 = x0, X1 = x1, W0 = w0s;
            x0  = sm00[e] * X0 + sm01[e] * X1 + sh0[e];
            x1  = sm10[e] * X0 + sm11[e] * X1 + sh1[e];
            w0s = fmaf(smw[e], W0, shw[e]);
        }
        float ev = __expf(-0.0008605f * (float)n0);
        for (int j = 0; j < KCH; ++j) {
            const int   n    = n0 + j;
            const float vn   = v_lds[n];
            const float an   = fmaf(dtZ, vn, betal);
            const float cn   = -dtZ * vn;
            const float det1 = an * dd - bb * cn;
            const float r1   = 1.0f / det1;
            const float s0   = c10 * ev;
            const float t0   = x0 + s0;
            const float nx0  = r1 * (dd * t0 - bb * x1);
            const float nx1  = r1 * fmaf(an, x1, -cn * t0);
            const float det = fmaf(D1, vn, D0);
            const float rd  = 1.0f / det;
            const float ow  = rd * (fmaf(d2, cs * ev, C4) - dtk4 * vn);
            w0s = fmaf(rd * d2, w0s, ow);
            const float w1n1 = Yc - v_lds[n + 1];
            out[0 * NT1 + 1 + n] = nx0;
            out[1 * NT1 + 1 + n] = nx1;
            out[3 * NT1 + 1 + n] = w0s - nx0;
            out[4 * NT1 + 1 + n] = w1n1 - nx1;
            x0 = nx0; x1 = nx1;
            ev *= rho;
        }
    }
    __threadfence();
    __syncthreads();

    // ---- stage 2: x2 scalar affine scan ----
    if (c < NCH) {
        float m2 = 1.0f, o2 = 0.0f;
        for (int j = 0; j < KCH; ++j) {
            const float x1v = out[1 * NT1 + 1 + n0 + j];
            m2 *= re2;
            o2 = fmaf(re2, o2, re2 * dtk5 * x1v);
        }
        smw[c] = m2; shw[c] = o2;
    }
    __syncthreads();
    for (int off = 1; off < NCH; off <<= 1) {
        float nm, no;
        const bool act = (c < NCH) && (c >= off);
        if (act) { nm = smw[c] * smw[c - off]; no = fmaf(smw[c], shw[c - off], shw[c]); }
        __syncthreads();
        if (act) { smw[c] = nm; shw[c] = no; }
        __syncthreads();
    }
    if (c < NCH) {
        float x2s = P0[2];
        if (c > 0) x2s = fmaf(smw[c - 1], x2s, shw[c - 1]);
        for (int j = 0; j < KCH; ++j) {
            const int n = n0 + j;
            const float x1v = out[1 * NT1 + 1 + n];
            x2s = re2 * fmaf(dtk5, x1v, x2s);
            out[2 * NT1 + 1 + n] = x2s;
        }
    }
    __threadfence();
    __syncthreads();

    // ---- stage 3: x5 scalar affine scan ----
    if (c < NCH) {
        float m3 = 1.0f, o3 = 0.0f;
        for (int j = 0; j < KCH; ++j) {
            const int n = n0 + j;
            const float x4v = out[4 * NT1 + 1 + n];
            const float x2v = out[2 * NT1 + 1 + n];
            const float qn  = fmaf(dtk5, x4v, dtlp * x2v);
            m3 *= re5;
            o3 = fmaf(re5, o3, re5 * qn);
        }
        smw[c] = m3; shw[c] = o3;
    }
    __syncthreads();
    for (int off = 1; off < NCH; off <<= 1) {
        float nm, no;
        const bool act = (c < NCH) && (c >= off);
        if (act) { nm = smw[c] * smw[c - off]; no = fmaf(smw[c], shw[c - off], shw[c]); }
        __syncthreads();
        if (act) { smw[c] = nm; shw[c] = no; }
        __syncthreads();
    }
    if (c < NCH) {
        float x5s = P0[5];
        if (c > 0) x5s = fmaf(smw[c - 1], x5s, shw[c - 1]);
        for (int j = 0; j < KCH; ++j) {
            const int n = n0 + j;
            const float x4v = out[4 * NT1 + 1 + n];
            const float x2v = out[2 * NT1 + 1 + n];
            x5s = re5 * (x5s + fmaf(dtk5, x4v, dtlp * x2v));
            out[5 * NT1 + 1 + n] = x5s;
        }
    }
}

extern "C" void kernel_launch(void* const* d_in, const int* in_sizes, int n_in,
                              void* d_out, int out_size, void* d_ws, size_t ws_size,
                              hipStream_t stream) {
    const float* theta = (const float*)d_in[0];
    const float* P0    = (const float*)d_in[1];
    float* out = (float*)d_out;
    hipLaunchKernelGGL(fwdode_kernel, dim3(1), dim3(BLOCK), 0, stream,
                       theta, P0, out);
}

// Round 4
// 36.829 us; speedup vs baseline: 30.3031x; 1.7174x over previous
//
#include <hip/hip_runtime.h>

#define NT    10000
#define NT1   10001
#define KCH   20
#define NCH   500      // phase-2: 500 chunks * 20 steps
#define CSH   250      // shooting: 250 chunks * 40 steps
#define LSH   40
#define NITER 5
#define BLOCK 512

// Multiple shooting for the closed (v,w0) recurrence + parallel affine scans
// for the full state, all scans done with in-wave __shfl_up (no barriers)
// plus a per-wave-total cross-wave prefix (1 barrier per scan).
__global__ __launch_bounds__(BLOCK)
void fwdode_kernel(const float* __restrict__ theta,
                   const float* __restrict__ P0,
                   float* __restrict__ out) {
    __shared__ float v_lds[NT1];
    __shared__ float gv[CSH], gw[CSH];
    __shared__ float ntw[4][6];   // Newton wave totals: J00,J01,J10,J11,r0,r1
    __shared__ float wt[8][8];    // stage1 totals: M00,M01,M10,M11,h0,h1,mw,hw
    __shared__ float s2t[8][2];   // stage2 totals: m,o
    __shared__ float s3t[8][2];   // stage3 totals: m,o

    const int tid  = threadIdx.x;
    const int lane = tid & 63;
    const int wv   = tid >> 6;

    const float dt = 0.1f, Zc = 46.0f, Yc = 2000.0f, lp = 7e-5f;
    const float k1 = theta[0], k2 = theta[1], k4 = theta[2],
                k5 = theta[3], k6 = theta[4];
    const float dtZ   = dt * Zc;
    const float dtZ2  = 2.0f * dtZ;
    const float beta  = 1.0f + dt * k2;
    const float d2    = 1.0f + dt * (k4 + k5);
    const float D0    = beta * d2;
    const float D1    = dtZ * (1.0f + dt * k5);
    const float E0    = beta * Yc * dt * (k4 + k5);
    const float E1    = beta + dt * dt * Zc * Yc * k5;
    const float C4    = dt * k4 * Yc;
    const float cs    = dt * k1 * 135.19f;
    const float c10   = dt * k1 * 122.9f;
    const float dtk4  = dt * k4;
    const float dtk5  = dt * k5;
    const float dtlp  = dt * lp;
    const float rho   = __expf(-0.0008605f);
    const float re2   = 1.0f / (1.0f + dt * (k6 + lp));
    const float re5   = 1.0f / (1.0f + dt * k6);
    const float dd    = d2 + dt * lp;
    const float bb    = -dtk4;
    const float betal = 1.0f + dt * (k2 + lp);

    // ---- background: T row + column 0 (waves 4-7) ----
    if (tid >= 256) {
        for (int i = tid - 256; i < NT1; i += 256)
            out[6 * NT1 + i] = (float)i * dt;
        if (tid - 256 < 6) out[(tid - 256) * NT1] = P0[tid - 256];
    }

    // ---- shooting init: slow-manifold closed-form guess ----
    if (tid < CSH) {
        float vi, wi;
        if (tid == 0) {
            vi = Yc - (P0[1] + P0[4]);
            wi = P0[0] + P0[3];
        } else {
            const float fm     = (float)(tid * LSH);
            const float rhon   = __expf(-0.0008605f * fm);
            const float alpha  = 1.0f / (1.0f + dtk5);
            const float alphan = __expf(fm * __logf(alpha));
            const float diff   = rho - alpha;
            float w1;
            if (__builtin_fabsf(diff) > 1e-4f)
                w1 = cs * alpha * (rhon - alphan) / diff;
            else
                w1 = cs * alpha * fm * rhon / rho;
            vi = Yc - w1;
            const float sm = cs * rhon;
            wi = (sm + dtk4 * w1) / (dt * k2 + dtZ * vi);
        }
        gv[tid] = vi; gw[tid] = wi;
    }

    // ---- Newton / multiple-shooting ----
    for (int it = 0; it < NITER; ++it) {
        __syncthreads();                       // guesses visible
        float J11 = 1.f, J12 = 0.f, J21 = 0.f, J22 = 1.f;
        float r0 = 0.f, r1 = 0.f;
        if (tid < CSH) {
            float v = gv[tid], w0 = gw[tid];
            float ev = __expf(-0.0008605f * (float)(tid * LSH));
            #pragma unroll 8
            for (int j = 0; j < LSH; ++j) {
                const float g    = fmaf(cs, ev, w0);
                const float det  = fmaf(D1, v, D0);
                const float rdet = __builtin_amdgcn_rcpf(det);
                const float h    = fmaf(-dtZ, g, E1);
                const float tq   = fmaf(dtZ, v, h);
                const float Nv   = fmaf(tq, v, E0);
                const float q    = fmaf(d2, g, C4);
                const float Nw   = fmaf(-dtk4, v, q);
                const float vn   = Nv * rdet;
                const float wn   = Nw * rdet;
                const float a11  = fmaf(-D1, vn, fmaf(dtZ2, v, h)) * rdet;
                const float a12  = (-dtZ * v) * rdet;
                const float a21  = -fmaf(D1, wn, dtk4) * rdet;
                const float a22  = d2 * rdet;
                const float t11 = a11 * J11 + a12 * J21;
                const float t12 = a11 * J12 + a12 * J22;
                const float t21 = a21 * J11 + a22 * J21;
                const float t22 = a21 * J12 + a22 * J22;
                J11 = t11; J12 = t12; J21 = t21; J22 = t22;
                v = vn; w0 = wn; ev *= rho;
            }
            if (tid < CSH - 1) { r0 = v - gv[tid + 1]; r1 = w0 - gw[tid + 1]; }
        }
        if (tid < 256) {
            // in-wave inclusive affine scan (self-after-earlier)
            #pragma unroll
            for (int off = 1; off < 64; off <<= 1) {
                const float e00 = __shfl_up(J11, off), e01 = __shfl_up(J12, off);
                const float e10 = __shfl_up(J21, off), e11 = __shfl_up(J22, off);
                const float f0  = __shfl_up(r0,  off), f1  = __shfl_up(r1,  off);
                if (lane >= off) {
                    const float n00 = J11*e00 + J12*e10, n01 = J11*e01 + J12*e11;
                    const float n10 = J21*e00 + J22*e10, n11 = J21*e01 + J22*e11;
                    const float g0  = J11*f0 + J12*f1 + r0;
                    const float g1  = J21*f0 + J22*f1 + r1;
                    J11 = n00; J12 = n01; J21 = n10; J22 = n11; r0 = g0; r1 = g1;
                }
            }
            if (lane == 63 && wv < 3) {
                ntw[wv][0] = J11; ntw[wv][1] = J12; ntw[wv][2] = J21;
                ntw[wv][3] = J22; ntw[wv][4] = r0;  ntw[wv][5] = r1;
            }
        }
        __syncthreads();                       // totals visible
        if (tid < 256) {
            float p0 = 0.f, p1 = 0.f;
            for (int ww = 0; ww < wv; ++ww) {
                const float q0 = ntw[ww][0]*p0 + ntw[ww][1]*p1 + ntw[ww][4];
                const float q1 = ntw[ww][2]*p0 + ntw[ww][3]*p1 + ntw[ww][5];
                p0 = q0; p1 = q1;
            }
            const float X00 = __shfl_up(J11, 1), X01 = __shfl_up(J12, 1);
            const float X10 = __shfl_up(J21, 1), X11 = __shfl_up(J22, 1);
            const float Y0  = __shfl_up(r0, 1),  Y1  = __shfl_up(r1, 1);
            float d0, d1;
            if (lane == 0) { d0 = p0; d1 = p1; }
            else { d0 = X00*p0 + X01*p1 + Y0; d1 = X10*p0 + X11*p1 + Y1; }
            if (tid > 0 && tid < CSH) { gv[tid] += d0; gw[tid] += d1; }
        }
    }
    __syncthreads();

    // ---- final pass: write v trajectory to LDS ----
    if (tid < CSH) {
        float v = gv[tid], w0 = gw[tid];
        float ev = __expf(-0.0008605f * (float)(tid * LSH));
        if (tid == 0) v_lds[0] = v;
        const int base = tid * LSH;
        #pragma unroll 8
        for (int j = 0; j < LSH; ++j) {
            const float g    = fmaf(cs, ev, w0);
            const float det  = fmaf(D1, v, D0);
            const float rdet = __builtin_amdgcn_rcpf(det);
            const float h    = fmaf(-dtZ, g, E1);
            const float tq   = fmaf(dtZ, v, h);
            const float Nv   = fmaf(tq, v, E0);
            const float q    = fmaf(d2, g, C4);
            const float Nw   = fmaf(-dtk4, v, q);
            v  = Nv * rdet;
            w0 = Nw * rdet;
            ev *= rho;
            v_lds[base + j + 1] = v;
        }
    }
    __syncthreads();

    // ---- Stage 1: (x0,x1) 2x2 affine + w0 scalar, shuffle scan ----
    const int n0 = tid * KCH;
    float M00 = 1.f, M01 = 0.f, M10 = 0.f, M11 = 1.f;
    float h0 = 0.f, h1 = 0.f, mw = 1.f, hw = 0.f;
    if (tid < NCH) {
        float ev = __expf(-0.0008605f * (float)n0);
        #pragma unroll 4
        for (int j = 0; j < KCH; ++j) {
            const int   n    = n0 + j;
            const float vn   = v_lds[n];
            const float an   = fmaf(dtZ, vn, betal);
            const float cn   = -dtZ * vn;
            const float det1 = an * dd - bb * cn;
            const float r1i  = 1.0f / det1;
            const float s0   = c10 * ev;
            const float A00 = r1i * dd,  A01 = -r1i * bb;
            const float A10 = -r1i * cn, A11 = r1i * an;
            const float nM00 = A00 * M00 + A01 * M10;
            const float nM01 = A00 * M01 + A01 * M11;
            const float nM10 = A10 * M00 + A11 * M10;
            const float nM11 = A10 * M01 + A11 * M11;
            const float nh0  = A00 * h0 + A01 * h1 + s0 * A00;
            const float nh1  = A10 * h0 + A11 * h1 + s0 * A10;
            M00 = nM00; M01 = nM01; M10 = nM10; M11 = nM11;
            h0 = nh0; h1 = nh1;
            const float det = fmaf(D1, vn, D0);
            const float rd  = 1.0f / det;
            const float pw  = rd * d2;
            const float ow  = rd * (fmaf(d2, cs * ev, C4) - dtk4 * vn);
            mw = pw * mw;
            hw = fmaf(pw, hw, ow);
            ev *= rho;
        }
    }
    #pragma unroll
    for (int off = 1; off < 64; off <<= 1) {
        const float e00 = __shfl_up(M00, off), e01 = __shfl_up(M01, off);
        const float e10 = __shfl_up(M10, off), e11 = __shfl_up(M11, off);
        const float f0  = __shfl_up(h0,  off), f1  = __shfl_up(h1,  off);
        const float em  = __shfl_up(mw,  off), eo  = __shfl_up(hw,  off);
        if (lane >= off) {
            const float n00 = M00*e00 + M01*e10, n01 = M00*e01 + M01*e11;
            const float n10 = M10*e00 + M11*e10, n11 = M10*e01 + M11*e11;
            const float g0  = M00*f0 + M01*f1 + h0;
            const float g1  = M10*f0 + M11*f1 + h1;
            const float nm  = mw * em, no = fmaf(mw, eo, hw);
            M00 = n00; M01 = n01; M10 = n10; M11 = n11;
            h0 = g0; h1 = g1; mw = nm; hw = no;
        }
    }
    if (lane == 63 && wv < 7) {
        wt[wv][0] = M00; wt[wv][1] = M01; wt[wv][2] = M10; wt[wv][3] = M11;
        wt[wv][4] = h0;  wt[wv][5] = h1;  wt[wv][6] = mw;  wt[wv][7] = hw;
    }
    __syncthreads();
    float p0 = P0[0], p1 = P0[1], pw0 = P0[0] + P0[3];
    for (int ww = 0; ww < wv; ++ww) {
        const float q0 = wt[ww][0]*p0 + wt[ww][1]*p1 + wt[ww][4];
        const float q1 = wt[ww][2]*p0 + wt[ww][3]*p1 + wt[ww][5];
        pw0 = fmaf(wt[ww][6], pw0, wt[ww][7]);
        p0 = q0; p1 = q1;
    }
    {
        const float X00 = __shfl_up(M00, 1), X01 = __shfl_up(M01, 1);
        const float X10 = __shfl_up(M10, 1), X11 = __shfl_up(M11, 1);
        const float Y0  = __shfl_up(h0, 1),  Y1  = __shfl_up(h1, 1);
        const float Zm  = __shfl_up(mw, 1),  Zo  = __shfl_up(hw, 1);
        float x0, x1, w0s;
        if (lane == 0) { x0 = p0; x1 = p1; w0s = pw0; }
        else {
            x0  = X00*p0 + X01*p1 + Y0;
            x1  = X10*p0 + X11*p1 + Y1;
            w0s = fmaf(Zm, pw0, Zo);
        }
        float x1r[KCH], x4r[KCH];
        if (tid < NCH) {
            float ev = __expf(-0.0008605f * (float)n0);
            #pragma unroll
            for (int j = 0; j < KCH; ++j) {
                const int   n    = n0 + j;
                const float vn   = v_lds[n];
                const float an   = fmaf(dtZ, vn, betal);
                const float cn   = -dtZ * vn;
                const float det1 = an * dd - bb * cn;
                const float r1i  = 1.0f / det1;
                const float s0   = c10 * ev;
                const float t0   = x0 + s0;
                const float nx0  = r1i * (dd * t0 - bb * x1);
                const float nx1  = r1i * fmaf(an, x1, -cn * t0);
                const float det = fmaf(D1, vn, D0);
                const float rd  = 1.0f / det;
                const float ow  = rd * (fmaf(d2, cs * ev, C4) - dtk4 * vn);
                w0s = fmaf(rd * d2, w0s, ow);
                const float w1n1 = Yc - v_lds[n + 1];
                const float x4v  = w1n1 - nx1;
                out[0 * NT1 + 1 + n] = nx0;
                out[1 * NT1 + 1 + n] = nx1;
                out[3 * NT1 + 1 + n] = w0s - nx0;
                out[4 * NT1 + 1 + n] = x4v;
                x1r[j] = nx1; x4r[j] = x4v;
                x0 = nx0; x1 = nx1;
                ev *= rho;
            }
        }

        // ---- Stage 2: x2 scalar affine scan (values from registers) ----
        float m2 = 1.f, o2 = 0.f;
        if (tid < NCH) {
            #pragma unroll
            for (int j = 0; j < KCH; ++j) {
                m2 *= re2;
                o2 = fmaf(re2, o2, re2 * dtk5 * x1r[j]);
            }
        }
        #pragma unroll
        for (int off = 1; off < 64; off <<= 1) {
            const float em = __shfl_up(m2, off), eo = __shfl_up(o2, off);
            if (lane >= off) { o2 = fmaf(m2, eo, o2); m2 *= em; }
        }
        if (lane == 63 && wv < 7) { s2t[wv][0] = m2; s2t[wv][1] = o2; }
        __syncthreads();
        float p2 = P0[2];
        for (int ww = 0; ww < wv; ++ww)
            p2 = fmaf(s2t[ww][0], p2, s2t[ww][1]);
        const float Em2 = __shfl_up(m2, 1), Eo2 = __shfl_up(o2, 1);
        float x2s = (lane == 0) ? p2 : fmaf(Em2, p2, Eo2);
        float x2r[KCH];
        if (tid < NCH) {
            #pragma unroll
            for (int j = 0; j < KCH; ++j) {
                x2s = re2 * fmaf(dtk5, x1r[j], x2s);
                out[2 * NT1 + 1 + n0 + j] = x2s;
                x2r[j] = x2s;
            }
        }

        // ---- Stage 3: x5 scalar affine scan (values from registers) ----
        float m3 = 1.f, o3 = 0.f;
        if (tid < NCH) {
            #pragma unroll
            for (int j = 0; j < KCH; ++j) {
                const float qn = fmaf(dtk5, x4r[j], dtlp * x2r[j]);
                m3 *= re5;
                o3 = fmaf(re5, o3, re5 * qn);
            }
        }
        #pragma unroll
        for (int off = 1; off < 64; off <<= 1) {
            const float em = __shfl_up(m3, off), eo = __shfl_up(o3, off);
            if (lane >= off) { o3 = fmaf(m3, eo, o3); m3 *= em; }
        }
        if (lane == 63 && wv < 7) { s3t[wv][0] = m3; s3t[wv][1] = o3; }
        __syncthreads();
        float p5 = P0[5];
        for (int ww = 0; ww < wv; ++ww)
            p5 = fmaf(s3t[ww][0], p5, s3t[ww][1]);
        const float Em3 = __shfl_up(m3, 1), Eo3 = __shfl_up(o3, 1);
        float x5s = (lane == 0) ? p5 : fmaf(Em3, p5, Eo3);
        if (tid < NCH) {
            #pragma unroll
            for (int j = 0; j < KCH; ++j) {
                const float qn = fmaf(dtk5, x4r[j], dtlp * x2r[j]);
                x5s = re5 * (x5s + qn);
                out[5 * NT1 + 1 + n0 + j] = x5s;
            }
        }
    }
}

extern "C" void kernel_launch(void* const* d_in, const int* in_sizes, int n_in,
                              void* d_out, int out_size, void* d_ws, size_t ws_size,
                              hipStream_t stream) {
    const float* theta = (const float*)d_in[0];
    const float* P0    = (const float*)d_in[1];
    float* out = (float*)d_out;
    hipLaunchKernelGGL(fwdode_kernel, dim3(1), dim3(BLOCK), 0, stream,
                       theta, P0, out);
}

// Round 5
// 25.498 us; speedup vs baseline: 43.7684x; 1.4444x over previous
//
#include <hip/hip_runtime.h>

#define NT    10000
#define NT1   10001
#define KCH   20
#define NCH   500      // 500 chunks * 20 steps, shared by shooting and output scans
#define NCORR 2        // Newton corrections (quadratic; guess err ~1%)
#define BLOCK 512

// Multiple shooting on the closed (v,w0) recurrence (w0=p0+p3, v=Y-(p1+p4)),
// then affine scans reconstruct the full 6-state trajectory. All scans are
// in-wave __shfl_up + a batched cross-wave prefix (1 barrier per scan).
// Final shooting integration is fused with the stage-1 scan-matrix build;
// per-step v,w0 live in registers (fully unrolled -> VGPRs).
__global__ __launch_bounds__(BLOCK)
void fwdode_kernel(const float* __restrict__ theta,
                   const float* __restrict__ P0,
                   float* __restrict__ out) {
    __shared__ float gv[NCH], gw[NCH];
    __shared__ float tw[7][6];   // wave totals: Newton (J,r) then stage1 (M,h)
    __shared__ float t2[7][2];   // stage2 totals
    __shared__ float t3[7][2];   // stage3 totals

    const int tid  = threadIdx.x;
    const int lane = tid & 63;
    const int wv   = tid >> 6;

    const float dt = 0.1f, Zc = 46.0f, Yc = 2000.0f, lp = 7e-5f;
    const float k1 = theta[0], k2 = theta[1], k4 = theta[2],
                k5 = theta[3], k6 = theta[4];
    const float dtZ   = dt * Zc;
    const float dtZ2  = 2.0f * dtZ;
    const float beta  = 1.0f + dt * k2;
    const float d2    = 1.0f + dt * (k4 + k5);
    const float D0    = beta * d2;
    const float D1    = dtZ * (1.0f + dt * k5);
    const float E0    = beta * Yc * dt * (k4 + k5);
    const float E1    = beta + dt * dt * Zc * Yc * k5;
    const float C4    = dt * k4 * Yc;
    const float cs    = dt * k1 * 135.19f;
    const float c10   = dt * k1 * 122.9f;
    const float dtk4  = dt * k4;
    const float dtk5  = dt * k5;
    const float dtlp  = dt * lp;
    const float lam   = 0.0008605f;
    const float rho   = __expf(-lam);
    const float re2   = 1.0f / (1.0f + dt * (k6 + lp));
    const float re5   = 1.0f / (1.0f + dt * k6);
    const float dd    = d2 + dt * lp;
    const float bb    = -dtk4;
    const float betal = 1.0f + dt * (k2 + lp);

    const float ev0 = __expf(-lam * (float)(tid * KCH));

    // ---- shooting init: slow-manifold closed-form guess ----
    if (tid < NCH) {
        float vi, wi;
        if (tid == 0) {
            vi = Yc - (P0[1] + P0[4]);
            wi = P0[0] + P0[3];
        } else {
            const float fm     = (float)(tid * KCH);
            const float rhon   = __expf(-lam * fm);
            const float alpha  = 1.0f / (1.0f + dtk5);
            const float alphan = __expf(fm * __logf(alpha));
            const float diff   = rho - alpha;
            float w1;
            if (__builtin_fabsf(diff) > 1e-4f)
                w1 = cs * alpha * (rhon - alphan) / diff;
            else
                w1 = cs * alpha * fm * rhon / rho;
            vi = Yc - w1;
            wi = (cs * rhon + dtk4 * w1) / (dt * k2 + dtZ * vi);
        }
        gv[tid] = vi; gw[tid] = wi;
    }

    // ---- Newton / multiple-shooting corrections ----
    for (int it = 0; it < NCORR; ++it) {
        __syncthreads();
        float J11 = 1.f, J12 = 0.f, J21 = 0.f, J22 = 1.f;
        float r0 = 0.f, r1 = 0.f;
        if (tid < NCH) {
            float v = gv[tid], w0 = gw[tid], ev = ev0;
            #pragma unroll
            for (int j = 0; j < KCH; ++j) {
                const float g    = fmaf(cs, ev, w0);
                const float det  = fmaf(D1, v, D0);
                const float rdet = __builtin_amdgcn_rcpf(det);
                const float h    = fmaf(-dtZ, g, E1);
                const float tq   = fmaf(dtZ, v, h);
                const float Nv   = fmaf(tq, v, E0);
                const float q    = fmaf(d2, g, C4);
                const float Nw   = fmaf(-dtk4, v, q);
                const float vn   = Nv * rdet;
                const float wn   = Nw * rdet;
                const float a11  = fmaf(-D1, vn, fmaf(dtZ2, v, h)) * rdet;
                const float a12  = (-dtZ * v) * rdet;
                const float a21  = -fmaf(D1, wn, dtk4) * rdet;
                const float a22  = d2 * rdet;
                const float t11 = a11 * J11 + a12 * J21;
                const float t12 = a11 * J12 + a12 * J22;
                const float t21 = a21 * J11 + a22 * J21;
                const float t22 = a21 * J12 + a22 * J22;
                J11 = t11; J12 = t12; J21 = t21; J22 = t22;
                v = vn; w0 = wn; ev *= rho;
            }
            if (tid < NCH - 1) { r0 = v - gv[tid + 1]; r1 = w0 - gw[tid + 1]; }
        }
        #pragma unroll
        for (int off = 1; off < 64; off <<= 1) {
            const float e00 = __shfl_up(J11, off), e01 = __shfl_up(J12, off);
            const float e10 = __shfl_up(J21, off), e11 = __shfl_up(J22, off);
            const float f0  = __shfl_up(r0,  off), f1  = __shfl_up(r1,  off);
            if (lane >= off) {
                const float n00 = J11*e00 + J12*e10, n01 = J11*e01 + J12*e11;
                const float n10 = J21*e00 + J22*e10, n11 = J21*e01 + J22*e11;
                const float g0  = J11*f0 + J12*f1 + r0;
                const float g1  = J21*f0 + J22*f1 + r1;
                J11 = n00; J12 = n01; J21 = n10; J22 = n11; r0 = g0; r1 = g1;
            }
        }
        if (lane == 63 && wv < 7) {
            tw[wv][0] = J11; tw[wv][1] = J12; tw[wv][2] = J21;
            tw[wv][3] = J22; tw[wv][4] = r0;  tw[wv][5] = r1;
        }
        __syncthreads();
        float p0 = 0.f, p1 = 0.f;
        #pragma unroll
        for (int ww = 0; ww < 7; ++ww) {
            const float T00 = tw[ww][0], T01 = tw[ww][1], T10 = tw[ww][2],
                        T11 = tw[ww][3], R0 = tw[ww][4],  R1 = tw[ww][5];
            if (ww < wv) {
                const float q0 = T00*p0 + T01*p1 + R0;
                const float q1 = T10*p0 + T11*p1 + R1;
                p0 = q0; p1 = q1;
            }
        }
        const float X00 = __shfl_up(J11, 1), X01 = __shfl_up(J12, 1);
        const float X10 = __shfl_up(J21, 1), X11 = __shfl_up(J22, 1);
        const float Y0  = __shfl_up(r0, 1),  Y1  = __shfl_up(r1, 1);
        float d0, d1;
        if (lane == 0) { d0 = p0; d1 = p1; }
        else { d0 = X00*p0 + X01*p1 + Y0; d1 = X10*p0 + X11*p1 + Y1; }
        if (tid > 0 && tid < NCH) { gv[tid] += d0; gw[tid] += d1; }
    }
    __syncthreads();

    // ---- final integration fused with stage-1 (x0,x1) matrix build ----
    float vr[KCH + 1], w0r[KCH];
    float M00 = 1.f, M01 = 0.f, M10 = 0.f, M11 = 1.f, h0 = 0.f, h1 = 0.f;
    if (tid < NCH) {
        float v = gv[tid], w0 = gw[tid], ev = ev0;
        vr[0] = v;
        #pragma unroll
        for (int j = 0; j < KCH; ++j) {
            // stage-1 step matrix from pre-step v
            const float an   = fmaf(dtZ, v, betal);
            const float cn   = -dtZ * v;
            const float det1 = fmaf(an, dd, -(bb * cn));
            const float r1i  = __builtin_amdgcn_rcpf(det1);
            const float s0   = c10 * ev;
            const float A00 = r1i * dd,  A01 = -r1i * bb;
            const float A10 = -r1i * cn, A11 = r1i * an;
            const float nM00 = A00*M00 + A01*M10, nM01 = A00*M01 + A01*M11;
            const float nM10 = A10*M00 + A11*M10, nM11 = A10*M01 + A11*M11;
            const float nh0  = A00*h0 + A01*h1 + s0*A00;
            const float nh1  = A10*h0 + A11*h1 + s0*A10;
            M00 = nM00; M01 = nM01; M10 = nM10; M11 = nM11; h0 = nh0; h1 = nh1;
            // exact (v,w0) step
            const float g    = fmaf(cs, ev, w0);
            const float det  = fmaf(D1, v, D0);
            const float rdet = __builtin_amdgcn_rcpf(det);
            const float h    = fmaf(-dtZ, g, E1);
            const float tq   = fmaf(dtZ, v, h);
            const float Nv   = fmaf(tq, v, E0);
            const float q    = fmaf(d2, g, C4);
            const float Nw   = fmaf(-dtk4, v, q);
            v  = Nv * rdet;
            w0 = Nw * rdet;
            vr[j + 1] = v; w0r[j] = w0;
            ev *= rho;
        }
    }
    #pragma unroll
    for (int off = 1; off < 64; off <<= 1) {
        const float e00 = __shfl_up(M00, off), e01 = __shfl_up(M01, off);
        const float e10 = __shfl_up(M10, off), e11 = __shfl_up(M11, off);
        const float f0  = __shfl_up(h0,  off), f1  = __shfl_up(h1,  off);
        if (lane >= off) {
            const float n00 = M00*e00 + M01*e10, n01 = M00*e01 + M01*e11;
            const float n10 = M10*e00 + M11*e10, n11 = M10*e01 + M11*e11;
            const float g0  = M00*f0 + M01*f1 + h0;
            const float g1  = M10*f0 + M11*f1 + h1;
            M00 = n00; M01 = n01; M10 = n10; M11 = n11; h0 = g0; h1 = g1;
        }
    }
    if (lane == 63 && wv < 7) {
        tw[wv][0] = M00; tw[wv][1] = M01; tw[wv][2] = M10;
        tw[wv][3] = M11; tw[wv][4] = h0;  tw[wv][5] = h1;
    }
    __syncthreads();
    float x1r[KCH], x2r[KCH];
    {
        float p0 = P0[0], p1 = P0[1];
        #pragma unroll
        for (int ww = 0; ww < 7; ++ww) {
            const float T00 = tw[ww][0], T01 = tw[ww][1], T10 = tw[ww][2],
                        T11 = tw[ww][3], R0 = tw[ww][4],  R1 = tw[ww][5];
            if (ww < wv) {
                const float q0 = T00*p0 + T01*p1 + R0;
                const float q1 = T10*p0 + T11*p1 + R1;
                p0 = q0; p1 = q1;
            }
        }
        const float X00 = __shfl_up(M00, 1), X01 = __shfl_up(M01, 1);
        const float X10 = __shfl_up(M10, 1), X11 = __shfl_up(M11, 1);
        const float Y0  = __shfl_up(h0, 1),  Y1  = __shfl_up(h1, 1);
        float x0, x1;
        if (lane == 0) { x0 = p0; x1 = p1; }
        else { x0 = X00*p0 + X01*p1 + Y0; x1 = X10*p0 + X11*p1 + Y1; }
        if (tid < NCH) {
            const int n0 = tid * KCH;
            float ev = ev0;
            #pragma unroll
            for (int j = 0; j < KCH; ++j) {
                const float vn   = vr[j];
                const float an   = fmaf(dtZ, vn, betal);
                const float cn   = -dtZ * vn;
                const float det1 = fmaf(an, dd, -(bb * cn));
                const float r1i  = __builtin_amdgcn_rcpf(det1);
                const float s0   = c10 * ev;
                const float t0   = x0 + s0;
                const float nx0  = r1i * (dd * t0 - bb * x1);
                const float nx1  = r1i * fmaf(an, x1, -cn * t0);
                const float x4v  = (Yc - vr[j + 1]) - nx1;
                out[0 * NT1 + 1 + n0 + j] = nx0;
                out[1 * NT1 + 1 + n0 + j] = nx1;
                out[3 * NT1 + 1 + n0 + j] = w0r[j] - nx0;
                out[4 * NT1 + 1 + n0 + j] = x4v;
                x1r[j] = nx1;
                x0 = nx0; x1 = nx1;
                ev *= rho;
            }
        }
    }

    // ---- stage 2: x2 scalar affine scan ----
    float m2 = 1.f, o2 = 0.f;
    if (tid < NCH) {
        #pragma unroll
        for (int j = 0; j < KCH; ++j) {
            m2 *= re2;
            o2 = fmaf(re2, o2, re2 * dtk5 * x1r[j]);
        }
    }
    #pragma unroll
    for (int off = 1; off < 64; off <<= 1) {
        const float em = __shfl_up(m2, off), eo = __shfl_up(o2, off);
        if (lane >= off) { o2 = fmaf(m2, eo, o2); m2 *= em; }
    }
    if (lane == 63 && wv < 7) { t2[wv][0] = m2; t2[wv][1] = o2; }
    __syncthreads();
    {
        float p2 = P0[2];
        #pragma unroll
        for (int ww = 0; ww < 7; ++ww) {
            const float Tm = t2[ww][0], To = t2[ww][1];
            if (ww < wv) p2 = fmaf(Tm, p2, To);
        }
        const float Em = __shfl_up(m2, 1), Eo = __shfl_up(o2, 1);
        float x2s = (lane == 0) ? p2 : fmaf(Em, p2, Eo);
        if (tid < NCH) {
            const int n0 = tid * KCH;
            #pragma unroll
            for (int j = 0; j < KCH; ++j) {
                x2s = re2 * fmaf(dtk5, x1r[j], x2s);
                out[2 * NT1 + 1 + n0 + j] = x2s;
                x2r[j] = x2s;
            }
        }
    }

    // ---- stage 3: x5 scalar affine scan ----
    float m3 = 1.f, o3 = 0.f;
    if (tid < NCH) {
        #pragma unroll
        for (int j = 0; j < KCH; ++j) {
            const float x4v = (Yc - vr[j + 1]) - x1r[j];
            const float qn  = fmaf(dtk5, x4v, dtlp * x2r[j]);
            m3 *= re5;
            o3 = fmaf(re5, o3, re5 * qn);
        }
    }
    #pragma unroll
    for (int off = 1; off < 64; off <<= 1) {
        const float em = __shfl_up(m3, off), eo = __shfl_up(o3, off);
        if (lane >= off) { o3 = fmaf(m3, eo, o3); m3 *= em; }
    }
    if (lane == 63 && wv < 7) { t3[wv][0] = m3; t3[wv][1] = o3; }
    __syncthreads();
    {
        float p5 = P0[5];
        #pragma unroll
        for (int ww = 0; ww < 7; ++ww) {
            const float Tm = t3[ww][0], To = t3[ww][1];
            if (ww < wv) p5 = fmaf(Tm, p5, To);
        }
        const float Em = __shfl_up(m3, 1), Eo = __shfl_up(o3, 1);
        float x5s = (lane == 0) ? p5 : fmaf(Em, p5, Eo);
        if (tid < NCH) {
            const int n0 = tid * KCH;
            #pragma unroll
            for (int j = 0; j < KCH; ++j) {
                const float x4v = (Yc - vr[j + 1]) - x1r[j];
                const float qn  = fmaf(dtk5, x4v, dtlp * x2r[j]);
                x5s = re5 * (x5s + qn);
                out[5 * NT1 + 1 + n0 + j] = x5s;
            }
        }
    }

    // ---- T row + column 0 ----
    for (int i = tid; i < NT1; i += BLOCK)
        out[6 * NT1 + i] = (float)i * dt;
    if (tid < 6) out[tid * NT1] = P0[tid];
}

extern "C" void kernel_launch(void* const* d_in, const int* in_sizes, int n_in,
                              void* d_out, int out_size, void* d_ws, size_t ws_size,
                              hipStream_t stream) {
    const float* theta = (const float*)d_in[0];
    const float* P0    = (const float*)d_in[1];
    float* out = (float*)d_out;
    hipLaunchKernelGGL(fwdode_kernel, dim3(1), dim3(BLOCK), 0, stream,
                       theta, P0, out);
}

// Round 6
// 24.856 us; speedup vs baseline: 44.9000x; 1.0259x over previous
//
#include <hip/hip_runtime.h>

#define NT    10000
#define NT1   10001
#define KCH   20
#define NCH   500      // 500 chunks * 20 steps
#define NCORR 2        // Newton corrections
#define BLOCK 512

// Multiple shooting on the closed (v,w0) recurrence (w0=p0+p3, v=Y-(p1+p4)),
// affine scans reconstruct the full 6-state trajectory (all in-wave __shfl_up
// + batched cross-wave prefix). Output rows are staged through LDS so global
// stores are lane-coalesced (scattered per-chunk stores were ~61k cache-line
// transactions through one CU ≈ 15-20us; coalesced is ~4k).
__global__ __launch_bounds__(BLOCK)
void fwdode_kernel(const float* __restrict__ theta,
                   const float* __restrict__ P0,
                   float* __restrict__ out) {
    __shared__ float gv[NCH], gw[NCH];
    __shared__ float tw[7][6];
    __shared__ float t2[7][2];
    __shared__ float t3[7][2];
    __shared__ float buf0[NT + 240], buf1[NT + 240];  // row staging (linear by col)

    const int tid  = threadIdx.x;
    const int lane = tid & 63;
    const int wv   = tid >> 6;

    const float dt = 0.1f, Zc = 46.0f, Yc = 2000.0f, lp = 7e-5f;
    const float k1 = theta[0], k2 = theta[1], k4 = theta[2],
                k5 = theta[3], k6 = theta[4];
    const float dtZ   = dt * Zc;
    const float dtZ2  = 2.0f * dtZ;
    const float beta  = 1.0f + dt * k2;
    const float d2    = 1.0f + dt * (k4 + k5);
    const float D0    = beta * d2;
    const float D1    = dtZ * (1.0f + dt * k5);
    const float E0    = beta * Yc * dt * (k4 + k5);
    const float E1    = beta + dt * dt * Zc * Yc * k5;
    const float C4    = dt * k4 * Yc;
    const float cs    = dt * k1 * 135.19f;
    const float c10   = dt * k1 * 122.9f;
    const float dtk4  = dt * k4;
    const float dtk5  = dt * k5;
    const float dtlp  = dt * lp;
    const float lam   = 0.0008605f;
    const float rho   = __expf(-lam);
    const float re2   = 1.0f / (1.0f + dt * (k6 + lp));
    const float re5   = 1.0f / (1.0f + dt * k6);
    const float dd    = d2 + dt * lp;
    const float bb    = -dtk4;
    const float betal = 1.0f + dt * (k2 + lp);

    const float ev0 = __expf(-lam * (float)(tid * KCH));

    // ---- shooting init: slow-manifold closed-form guess ----
    if (tid < NCH) {
        float vi, wi;
        if (tid == 0) {
            vi = Yc - (P0[1] + P0[4]);
            wi = P0[0] + P0[3];
        } else {
            const float fm     = (float)(tid * KCH);
            const float rhon   = __expf(-lam * fm);
            const float alpha  = 1.0f / (1.0f + dtk5);
            const float alphan = __expf(fm * __logf(alpha));
            const float diff   = rho - alpha;
            float w1;
            if (__builtin_fabsf(diff) > 1e-4f)
                w1 = cs * alpha * (rhon - alphan) / diff;
            else
                w1 = cs * alpha * fm * rhon / rho;
            vi = Yc - w1;
            wi = (cs * rhon + dtk4 * w1) / (dt * k2 + dtZ * vi);
        }
        gv[tid] = vi; gw[tid] = wi;
    }

    // ---- Newton / multiple-shooting corrections ----
    for (int it = 0; it < NCORR; ++it) {
        __syncthreads();
        float J11 = 1.f, J12 = 0.f, J21 = 0.f, J22 = 1.f;
        float r0 = 0.f, r1 = 0.f;
        if (tid < NCH) {
            float v = gv[tid], w0 = gw[tid], ev = ev0;
            #pragma unroll
            for (int j = 0; j < KCH; ++j) {
                const float g    = fmaf(cs, ev, w0);
                const float det  = fmaf(D1, v, D0);
                const float rdet = __builtin_amdgcn_rcpf(det);
                const float h    = fmaf(-dtZ, g, E1);
                const float tq   = fmaf(dtZ, v, h);
                const float Nv   = fmaf(tq, v, E0);
                const float q    = fmaf(d2, g, C4);
                const float Nw   = fmaf(-dtk4, v, q);
                const float vn   = Nv * rdet;
                const float wn   = Nw * rdet;
                const float a11  = fmaf(-D1, vn, fmaf(dtZ2, v, h)) * rdet;
                const float a12  = (-dtZ * v) * rdet;
                const float a21  = -fmaf(D1, wn, dtk4) * rdet;
                const float a22  = d2 * rdet;
                const float t11 = a11 * J11 + a12 * J21;
                const float t12 = a11 * J12 + a12 * J22;
                const float t21 = a21 * J11 + a22 * J21;
                const float t22 = a21 * J12 + a22 * J22;
                J11 = t11; J12 = t12; J21 = t21; J22 = t22;
                v = vn; w0 = wn; ev *= rho;
            }
            if (tid < NCH - 1) { r0 = v - gv[tid + 1]; r1 = w0 - gw[tid + 1]; }
        }
        #pragma unroll
        for (int off = 1; off < 64; off <<= 1) {
            const float e00 = __shfl_up(J11, off), e01 = __shfl_up(J12, off);
            const float e10 = __shfl_up(J21, off), e11 = __shfl_up(J22, off);
            const float f0  = __shfl_up(r0,  off), f1  = __shfl_up(r1,  off);
            if (lane >= off) {
                const float n00 = J11*e00 + J12*e10, n01 = J11*e01 + J12*e11;
                const float n10 = J21*e00 + J22*e10, n11 = J21*e01 + J22*e11;
                const float g0  = J11*f0 + J12*f1 + r0;
                const float g1  = J21*f0 + J22*f1 + r1;
                J11 = n00; J12 = n01; J21 = n10; J22 = n11; r0 = g0; r1 = g1;
            }
        }
        if (lane == 63 && wv < 7) {
            tw[wv][0] = J11; tw[wv][1] = J12; tw[wv][2] = J21;
            tw[wv][3] = J22; tw[wv][4] = r0;  tw[wv][5] = r1;
        }
        __syncthreads();
        float p0 = 0.f, p1 = 0.f;
        #pragma unroll
        for (int ww = 0; ww < 7; ++ww) {
            const float T00 = tw[ww][0], T01 = tw[ww][1], T10 = tw[ww][2],
                        T11 = tw[ww][3], R0 = tw[ww][4],  R1 = tw[ww][5];
            if (ww < wv) {
                const float q0 = T00*p0 + T01*p1 + R0;
                const float q1 = T10*p0 + T11*p1 + R1;
                p0 = q0; p1 = q1;
            }
        }
        const float X00 = __shfl_up(J11, 1), X01 = __shfl_up(J12, 1);
        const float X10 = __shfl_up(J21, 1), X11 = __shfl_up(J22, 1);
        const float Y0  = __shfl_up(r0, 1),  Y1  = __shfl_up(r1, 1);
        float d0, d1;
        if (lane == 0) { d0 = p0; d1 = p1; }
        else { d0 = X00*p0 + X01*p1 + Y0; d1 = X10*p0 + X11*p1 + Y1; }
        if (tid > 0 && tid < NCH) { gv[tid] += d0; gw[tid] += d1; }
    }
    __syncthreads();

    // ---- final integration fused with stage-1 (x0,x1) matrix build ----
    float vr[KCH + 1], w0r[KCH];
    float M00 = 1.f, M01 = 0.f, M10 = 0.f, M11 = 1.f, h0 = 0.f, h1 = 0.f;
    if (tid < NCH) {
        float v = gv[tid], w0 = gw[tid], ev = ev0;
        vr[0] = v;
        #pragma unroll
        for (int j = 0; j < KCH; ++j) {
            const float an   = fmaf(dtZ, v, betal);
            const float cn   = -dtZ * v;
            const float det1 = fmaf(an, dd, -(bb * cn));
            const float r1i  = __builtin_amdgcn_rcpf(det1);
            const float s0   = c10 * ev;
            const float A00 = r1i * dd,  A01 = -r1i * bb;
            const float A10 = -r1i * cn, A11 = r1i * an;
            const float nM00 = A00*M00 + A01*M10, nM01 = A00*M01 + A01*M11;
            const float nM10 = A10*M00 + A11*M10, nM11 = A10*M01 + A11*M11;
            const float nh0  = A00*h0 + A01*h1 + s0*A00;
            const float nh1  = A10*h0 + A11*h1 + s0*A10;
            M00 = nM00; M01 = nM01; M10 = nM10; M11 = nM11; h0 = nh0; h1 = nh1;
            const float g    = fmaf(cs, ev, w0);
            const float det  = fmaf(D1, v, D0);
            const float rdet = __builtin_amdgcn_rcpf(det);
            const float h    = fmaf(-dtZ, g, E1);
            const float tq   = fmaf(dtZ, v, h);
            const float Nv   = fmaf(tq, v, E0);
            const float q    = fmaf(d2, g, C4);
            const float Nw   = fmaf(-dtk4, v, q);
            v  = Nv * rdet;
            w0 = Nw * rdet;
            vr[j + 1] = v; w0r[j] = w0;
            ev *= rho;
        }
    }
    #pragma unroll
    for (int off = 1; off < 64; off <<= 1) {
        const float e00 = __shfl_up(M00, off), e01 = __shfl_up(M01, off);
        const float e10 = __shfl_up(M10, off), e11 = __shfl_up(M11, off);
        const float f0  = __shfl_up(h0,  off), f1  = __shfl_up(h1,  off);
        if (lane >= off) {
            const float n00 = M00*e00 + M01*e10, n01 = M00*e01 + M01*e11;
            const float n10 = M10*e00 + M11*e10, n11 = M10*e01 + M11*e11;
            const float g0  = M00*f0 + M01*f1 + h0;
            const float g1  = M10*f0 + M11*f1 + h1;
            M00 = n00; M01 = n01; M10 = n10; M11 = n11; h0 = g0; h1 = g1;
        }
    }
    if (lane == 63 && wv < 7) {
        tw[wv][0] = M00; tw[wv][1] = M01; tw[wv][2] = M10;
        tw[wv][3] = M11; tw[wv][4] = h0;  tw[wv][5] = h1;
    }
    __syncthreads();
    float x0r[KCH], x1r[KCH], x2r[KCH];
    {
        float p0 = P0[0], p1 = P0[1];
        #pragma unroll
        for (int ww = 0; ww < 7; ++ww) {
            const float T00 = tw[ww][0], T01 = tw[ww][1], T10 = tw[ww][2],
                        T11 = tw[ww][3], R0 = tw[ww][4],  R1 = tw[ww][5];
            if (ww < wv) {
                const float q0 = T00*p0 + T01*p1 + R0;
                const float q1 = T10*p0 + T11*p1 + R1;
                p0 = q0; p1 = q1;
            }
        }
        const float X00 = __shfl_up(M00, 1), X01 = __shfl_up(M01, 1);
        const float X10 = __shfl_up(M10, 1), X11 = __shfl_up(M11, 1);
        const float Y0  = __shfl_up(h0, 1),  Y1  = __shfl_up(h1, 1);
        float x0, x1;
        if (lane == 0) { x0 = p0; x1 = p1; }
        else { x0 = X00*p0 + X01*p1 + Y0; x1 = X10*p0 + X11*p1 + Y1; }
        if (tid < NCH) {
            float ev = ev0;
            #pragma unroll
            for (int j = 0; j < KCH; ++j) {
                const float vn   = vr[j];
                const float an   = fmaf(dtZ, vn, betal);
                const float cn   = -dtZ * vn;
                const float det1 = fmaf(an, dd, -(bb * cn));
                const float r1i  = __builtin_amdgcn_rcpf(det1);
                const float s0   = c10 * ev;
                const float t0   = x0 + s0;
                const float nx0  = r1i * (dd * t0 - bb * x1);
                const float nx1  = r1i * fmaf(an, x1, -cn * t0);
                x0r[j] = nx0; x1r[j] = nx1;
                x0 = nx0; x1 = nx1;
                ev *= rho;
            }
        }
    }

    // ---- phase A: stage rows 0,1 -> coalesced write ----
    if (tid < NCH) {
        const int n0 = tid * KCH;
        #pragma unroll
        for (int j = 0; j < KCH; ++j) { buf0[n0 + j] = x0r[j]; buf1[n0 + j] = x1r[j]; }
    }
    __syncthreads();
    for (int e = tid; e < NT; e += BLOCK) {
        out[0 * NT1 + 1 + e] = buf0[e];
        out[1 * NT1 + 1 + e] = buf1[e];
    }
    __syncthreads();

    // ---- stage 2: x2 scalar affine scan ----
    float m2 = 1.f, o2 = 0.f;
    if (tid < NCH) {
        #pragma unroll
        for (int j = 0; j < KCH; ++j) {
            m2 *= re2;
            o2 = fmaf(re2, o2, re2 * dtk5 * x1r[j]);
        }
    }
    #pragma unroll
    for (int off = 1; off < 64; off <<= 1) {
        const float em = __shfl_up(m2, off), eo = __shfl_up(o2, off);
        if (lane >= off) { o2 = fmaf(m2, eo, o2); m2 *= em; }
    }
    if (lane == 63 && wv < 7) { t2[wv][0] = m2; t2[wv][1] = o2; }
    __syncthreads();
    {
        float p2 = P0[2];
        #pragma unroll
        for (int ww = 0; ww < 7; ++ww) {
            const float Tm = t2[ww][0], To = t2[ww][1];
            if (ww < wv) p2 = fmaf(Tm, p2, To);
        }
        const float Em = __shfl_up(m2, 1), Eo = __shfl_up(o2, 1);
        float x2s = (lane == 0) ? p2 : fmaf(Em, p2, Eo);
        if (tid < NCH) {
            #pragma unroll
            for (int j = 0; j < KCH; ++j) {
                x2s = re2 * fmaf(dtk5, x1r[j], x2s);
                x2r[j] = x2s;
            }
        }
    }

    // ---- stage 3: x5 scalar affine scan ----
    float m3 = 1.f, o3 = 0.f;
    if (tid < NCH) {
        #pragma unroll
        for (int j = 0; j < KCH; ++j) {
            const float x4v = (Yc - vr[j + 1]) - x1r[j];
            const float qn  = fmaf(dtk5, x4v, dtlp * x2r[j]);
            m3 *= re5;
            o3 = fmaf(re5, o3, re5 * qn);
        }
    }
    #pragma unroll
    for (int off = 1; off < 64; off <<= 1) {
        const float em = __shfl_up(m3, off), eo = __shfl_up(o3, off);
        if (lane >= off) { o3 = fmaf(m3, eo, o3); m3 *= em; }
    }
    if (lane == 63 && wv < 7) { t3[wv][0] = m3; t3[wv][1] = o3; }
    __syncthreads();
    {
        float p5 = P0[5];
        #pragma unroll
        for (int ww = 0; ww < 7; ++ww) {
            const float Tm = t3[ww][0], To = t3[ww][1];
            if (ww < wv) p5 = fmaf(Tm, p5, To);
        }
        const float Em = __shfl_up(m3, 1), Eo = __shfl_up(o3, 1);
        float x5s = (lane == 0) ? p5 : fmaf(Em, p5, Eo);
        if (tid < NCH) {
            const int n0 = tid * KCH;
            #pragma unroll
            for (int j = 0; j < KCH; ++j) {
                const float x4v = (Yc - vr[j + 1]) - x1r[j];
                const float qn  = fmaf(dtk5, x4v, dtlp * x2r[j]);
                x5s = re5 * (x5s + qn);
                buf0[n0 + j] = x2r[j];
                buf1[n0 + j] = x5s;
            }
        }
    }
    __syncthreads();

    // ---- phase B: coalesced write rows 2,5 ----
    for (int e = tid; e < NT; e += BLOCK) {
        out[2 * NT1 + 1 + e] = buf0[e];
        out[5 * NT1 + 1 + e] = buf1[e];
    }
    __syncthreads();

    // ---- phase C: stage rows 3,4 -> coalesced write ----
    if (tid < NCH) {
        const int n0 = tid * KCH;
        #pragma unroll
        for (int j = 0; j < KCH; ++j) {
            buf0[n0 + j] = w0r[j] - x0r[j];
            buf1[n0 + j] = (Yc - vr[j + 1]) - x1r[j];
        }
    }
    __syncthreads();
    for (int e = tid; e < NT; e += BLOCK) {
        out[3 * NT1 + 1 + e] = buf0[e];
        out[4 * NT1 + 1 + e] = buf1[e];
    }

    // ---- T row + column 0 (coalesced) ----
    for (int i = tid; i < NT1; i += BLOCK)
        out[6 * NT1 + i] = (float)i * dt;
    if (tid < 6) out[tid * NT1] = P0[tid];
}

extern "C" void kernel_launch(void* const* d_in, const int* in_sizes, int n_in,
                              void* d_out, int out_size, void* d_ws, size_t ws_size,
                              hipStream_t stream) {
    const float* theta = (const float*)d_in[0];
    const float* P0    = (const float*)d_in[1];
    float* out = (float*)d_out;
    hipLaunchKernelGGL(fwdode_kernel, dim3(1), dim3(BLOCK), 0, stream,
                       theta, P0, out);
}